// Round 1
// baseline (558.316 us; speedup 1.0000x reference)
//
#include <hip/hip_runtime.h>
#include <hip/hip_bf16.h>
#include <stdint.h>

typedef __attribute__((ext_vector_type(8))) __bf16 bf16x8;
typedef __attribute__((ext_vector_type(4))) float f32x4;

#define MFMA16(a, b, c) __builtin_amdgcn_mfma_f32_16x16x32_bf16((a), (b), (c), 0, 0, 0)

static __device__ __forceinline__ void gload_lds16(const void* g, void* l) {
  __builtin_amdgcn_global_load_lds(
      reinterpret_cast<const __attribute__((address_space(1))) uint32_t*>(
          reinterpret_cast<uintptr_t>(g)),
      reinterpret_cast<__attribute__((address_space(3))) uint32_t*>(
          reinterpret_cast<uintptr_t>(l)),
      16, 0, 0);
}

// ---------------- fp32 -> bf16 copy convert (vectorized) ----------------
__global__ void cvt_f32_bf16(const float* __restrict__ in, __bf16* __restrict__ out, int n) {
  int i = (blockIdx.x * blockDim.x + threadIdx.x) * 8;
  if (i >= n) return;
  float4 a = *(const float4*)(in + i);
  float4 b = *(const float4*)(in + i + 4);
  bf16x8 o;
  o[0] = (__bf16)a.x; o[1] = (__bf16)a.y; o[2] = (__bf16)a.z; o[3] = (__bf16)a.w;
  o[4] = (__bf16)b.x; o[5] = (__bf16)b.y; o[6] = (__bf16)b.z; o[7] = (__bf16)b.w;
  *(bf16x8*)(out + i) = o;
}

// ---------- transpose + convert: in[R][C] f32 -> out[C][R] bf16 ----------
__global__ void transpose_cvt(const float* __restrict__ in, __bf16* __restrict__ out,
                              int R, int C) {
  __shared__ float tile[32][33];
  int c0 = blockIdx.x * 32, r0 = blockIdx.y * 32;
  int tx = threadIdx.x, ty = threadIdx.y;  // 32 x 8
#pragma unroll
  for (int i = 0; i < 4; i++)
    tile[ty + i * 8][tx] = in[(size_t)(r0 + ty + i * 8) * C + c0 + tx];
  __syncthreads();
#pragma unroll
  for (int i = 0; i < 4; i++)
    out[(size_t)(c0 + ty + i * 8) * R + r0 + tx] = (__bf16)tile[tx][ty + i * 8];
}

// ---------- V [BH][2048][64] -> Vt [BH][64][2048] (bf16) ----------
__global__ void transpose_v(const __bf16* __restrict__ V, __bf16* __restrict__ Vt) {
  __shared__ __bf16 tile[64][72];
  int bh = blockIdx.y, s0 = blockIdx.x * 64;
  int t = threadIdx.x;          // 256
  int r = t >> 2, cq = (t & 3) * 16;
  const __bf16* src = V + ((size_t)bh * 2048 + s0 + r) * 64 + cq;
  bf16x8 v0 = *(const bf16x8*)src;
  bf16x8 v1 = *(const bf16x8*)(src + 8);
#pragma unroll
  for (int j = 0; j < 8; j++) { tile[r][cq + j] = v0[j]; tile[r][cq + 8 + j] = v1[j]; }
  __syncthreads();
  int d = t >> 2, sq = (t & 3) * 16;
  bf16x8 o0, o1;
#pragma unroll
  for (int j = 0; j < 8; j++) { o0[j] = tile[sq + j][d]; o1[j] = tile[sq + 8 + j][d]; }
  __bf16* dst = Vt + ((size_t)bh * 64 + d) * 2048 + s0 + sq;
  *(bf16x8*)dst = o0;
  *(bf16x8*)(dst + 8) = o1;
}

// ---------------- GEMM: C[M,N] = A[M,1024] @ Bt[N,1024]^T ----------------
// m97 structure: 128x128 tile, 4 waves (2x2), BK=32, global_load_lds(16B).
// EPI==0: scatter to Q/K/V [B=4,H=16,S=2048,64] bf16 (+bias)
// EPI==1: plain fp32 store to Cf [M,N] (+bias)
template <int EPI>
__global__ __launch_bounds__(256) void gemm_bt(
    const __bf16* __restrict__ A, const __bf16* __restrict__ Bt,
    const float* __restrict__ bias, float* __restrict__ Cf,
    __bf16* __restrict__ Qb, __bf16* __restrict__ Kb, __bf16* __restrict__ Vb, int N) {
  __shared__ __bf16 lA[128 * 32];
  __shared__ __bf16 lB[128 * 32];
  const int tM = blockIdx.x, tN = blockIdx.y;
  const int tid = threadIdx.x;
  const int w = tid >> 6, lane = tid & 63;
  const int wr = w >> 1, wc = w & 1;
  const int lr = lane & 15, lg = lane >> 4;

  // staging: wave w stages 1KB chunks {w, w+4} of each tile
  const __bf16* As0 = A + (size_t)(tM * 128 + w * 16 + (lane >> 2)) * 1024 + (lane & 3) * 8;
  const __bf16* Bs0 = Bt + (size_t)(tN * 128 + w * 16 + (lane >> 2)) * 1024 + (lane & 3) * 8;
  __bf16* lA0 = &lA[w * 512];
  __bf16* lA1 = &lA[w * 512 + 2048];
  __bf16* lB0 = &lB[w * 512];
  __bf16* lB1 = &lB[w * 512 + 2048];

  f32x4 acc[4][4];
#pragma unroll
  for (int m = 0; m < 4; m++)
#pragma unroll
    for (int n = 0; n < 4; n++) acc[m][n] = f32x4{0.f, 0.f, 0.f, 0.f};

  for (int k0 = 0; k0 < 1024; k0 += 32) {
    gload_lds16(As0 + k0, lA0);
    gload_lds16(As0 + 64 * 1024 + k0, lA1);
    gload_lds16(Bs0 + k0, lB0);
    gload_lds16(Bs0 + 64 * 1024 + k0, lB1);
    __syncthreads();
    bf16x8 af[4], bfr[4];
#pragma unroll
    for (int m = 0; m < 4; m++)
      af[m] = *(const bf16x8*)&lA[(wr * 64 + m * 16 + lr) * 32 + lg * 8];
#pragma unroll
    for (int n = 0; n < 4; n++)
      bfr[n] = *(const bf16x8*)&lB[(wc * 64 + n * 16 + lr) * 32 + lg * 8];
#pragma unroll
    for (int m = 0; m < 4; m++)
#pragma unroll
      for (int n = 0; n < 4; n++) acc[m][n] = MFMA16(af[m], bfr[n], acc[m][n]);
    __syncthreads();
  }

#pragma unroll
  for (int m = 0; m < 4; m++) {
#pragma unroll
    for (int n = 0; n < 4; n++) {
      int row0 = tM * 128 + wr * 64 + m * 16 + lg * 4;
      int col = tN * 128 + wc * 64 + n * 16 + lr;
      float bv = bias[col];
      if (EPI == 0) {
        int which = col >> 10, rem = col & 1023;
        int hh = rem >> 6, dd = rem & 63;
        __bf16* dst = (which == 0) ? Qb : ((which == 1) ? Kb : Vb);
#pragma unroll
        for (int r = 0; r < 4; r++) {
          int row = row0 + r;
          int b = row >> 11, s = row & 2047;
          dst[((size_t)(b * 16 + hh) * 2048 + s) * 64 + dd] = (__bf16)(acc[m][n][r] + bv);
        }
      } else {
#pragma unroll
        for (int r = 0; r < 4; r++)
          Cf[(size_t)(row0 + r) * N + col] = acc[m][n][r] + bv;
      }
    }
  }
}

// ---------------- flash causal attention ----------------
// grid: (32 q-blocks [reversed], 64 bh), block 256 (4 waves x 16 q-rows).
// Q,K: [BH][2048][64] bf16; Vt: [BH][64][2048] bf16; Y: [B,S,1024] bf16
__global__ __launch_bounds__(256) void attn_fwd(
    const __bf16* __restrict__ Q, const __bf16* __restrict__ K,
    const __bf16* __restrict__ Vt, __bf16* __restrict__ Y) {
  const int qb = (int)gridDim.x - 1 - (int)blockIdx.x;  // big tiles dispatch first
  const int bh = blockIdx.y;
  const int w = threadIdx.x >> 6, lane = threadIdx.x & 63;
  const int lr = lane & 15, lg = lane >> 4;
  const int b = bh >> 4, h = bh & 15;
  const int qbase = qb * 64 + w * 16;
  const __bf16* Qp = Q + (size_t)bh * 2048 * 64;
  const __bf16* Kp = K + (size_t)bh * 2048 * 64;
  const __bf16* Vp = Vt + (size_t)bh * 64 * 2048;

  bf16x8 aq[2];
#pragma unroll
  for (int c = 0; c < 2; c++)
    aq[c] = *(const bf16x8*)&Qp[(size_t)(qbase + lr) * 64 + c * 32 + lg * 8];

  f32x4 acc_o[4];
#pragma unroll
  for (int dn = 0; dn < 4; dn++) acc_o[dn] = f32x4{0.f, 0.f, 0.f, 0.f};
  float m_run[4], l_run[4];
#pragma unroll
  for (int r = 0; r < 4; r++) { m_run[r] = -1e30f; l_run[r] = 0.f; }

  __shared__ __bf16 Plds[4][16 * 72];  // per-wave private, stride 144B (2-way only)
  __bf16* Pw = Plds[w];
  const float scale = 0.125f;
  const int kvend = (qb + 1) * 64;

  for (int kv0 = 0; kv0 < kvend; kv0 += 64) {
    f32x4 s4[4];
#pragma unroll
    for (int n = 0; n < 4; n++) s4[n] = f32x4{0.f, 0.f, 0.f, 0.f};
#pragma unroll
    for (int c = 0; c < 2; c++) {
#pragma unroll
      for (int n = 0; n < 4; n++) {
        bf16x8 bk = *(const bf16x8*)&Kp[(size_t)(kv0 + n * 16 + lr) * 64 + c * 32 + lg * 8];
        s4[n] = MFMA16(aq[c], bk, s4[n]);
      }
    }
    float p[4][4];
#pragma unroll
    for (int r = 0; r < 4; r++) {
      const int qrow = qbase + lg * 4 + r;
      float vmax = -1e30f;
#pragma unroll
      for (int n = 0; n < 4; n++) {
        float sv = s4[n][r] * scale;
        if (kv0 + n * 16 + lr > qrow) sv = -1e30f;  // causal mask
        p[n][r] = sv;
        vmax = fmaxf(vmax, sv);
      }
      vmax = fmaxf(vmax, __shfl_xor(vmax, 1));
      vmax = fmaxf(vmax, __shfl_xor(vmax, 2));
      vmax = fmaxf(vmax, __shfl_xor(vmax, 4));
      vmax = fmaxf(vmax, __shfl_xor(vmax, 8));
      float mnew = fmaxf(m_run[r], vmax);
      float alpha = __expf(m_run[r] - mnew);
      m_run[r] = mnew;
      float rsum = 0.f;
#pragma unroll
      for (int n = 0; n < 4; n++) {
        float e = __expf(p[n][r] - mnew);
        p[n][r] = e;
        rsum += e;
      }
      rsum += __shfl_xor(rsum, 1);
      rsum += __shfl_xor(rsum, 2);
      rsum += __shfl_xor(rsum, 4);
      rsum += __shfl_xor(rsum, 8);
      l_run[r] = l_run[r] * alpha + rsum;
#pragma unroll
      for (int dn = 0; dn < 4; dn++) acc_o[dn][r] *= alpha;
    }
    // P (C-layout) -> LDS -> A-layout fragments
#pragma unroll
    for (int r = 0; r < 4; r++)
#pragma unroll
      for (int n = 0; n < 4; n++)
        Pw[(lg * 4 + r) * 72 + n * 16 + lr] = (__bf16)p[n][r];
    bf16x8 ap[2];
    ap[0] = *(const bf16x8*)&Pw[lr * 72 + lg * 8];
    ap[1] = *(const bf16x8*)&Pw[lr * 72 + 32 + lg * 8];
#pragma unroll
    for (int dn = 0; dn < 4; dn++) {
#pragma unroll
      for (int c = 0; c < 2; c++) {
        bf16x8 bv = *(const bf16x8*)&Vp[(size_t)(dn * 16 + lr) * 2048 + kv0 + c * 32 + lg * 8];
        acc_o[dn] = MFMA16(c ? ap[1] : ap[0], bv, acc_o[dn]);
      }
    }
  }
#pragma unroll
  for (int r = 0; r < 4; r++) {
    float inv = 1.f / l_run[r];
    int row = b * 2048 + qbase + lg * 4 + r;
#pragma unroll
    for (int dn = 0; dn < 4; dn++)
      Y[(size_t)row * 1024 + h * 64 + dn * 16 + lr] = (__bf16)(acc_o[dn][r] * inv);
  }
}

extern "C" void kernel_launch(void* const* d_in, const int* in_sizes, int n_in,
                              void* d_out, int out_size, void* d_ws, size_t ws_size,
                              hipStream_t stream) {
  const float* x = (const float*)d_in[0];
  const float* wqkv = (const float*)d_in[1];
  const float* bqkv = (const float*)d_in[2];
  const float* wo = (const float*)d_in[3];
  const float* bo = (const float*)d_in[4];
  float* out = (float*)d_out;

  __bf16* ws = (__bf16*)d_ws;
  __bf16* xb = ws;                      // 8,388,608 elems (reused as Y later)
  __bf16* wqkvT = xb + 8388608;         // 3,145,728
  __bf16* woT = wqkvT + 3145728;        // 1,048,576
  __bf16* Qb = woT + 1048576;           // 8,388,608
  __bf16* Kb = Qb + 8388608;            // 8,388,608
  __bf16* Vb = Kb + 8388608;            // 8,388,608
  __bf16* Vtb = Vb + 8388608;           // 8,388,608
  __bf16* Yb = xb;                      // alias: xb dead after gemm1

  cvt_f32_bf16<<<4096, 256, 0, stream>>>(x, xb, 8388608);
  dim3 tb(32, 8);
  transpose_cvt<<<dim3(96, 32), tb, 0, stream>>>(wqkv, wqkvT, 1024, 3072);
  transpose_cvt<<<dim3(32, 32), tb, 0, stream>>>(wo, woT, 1024, 1024);
  gemm_bt<0><<<dim3(64, 24), 256, 0, stream>>>(xb, wqkvT, bqkv, nullptr, Qb, Kb, Vb, 3072);
  transpose_v<<<dim3(32, 64), 256, 0, stream>>>(Vb, Vtb);
  attn_fwd<<<dim3(32, 64), 256, 0, stream>>>(Qb, Kb, Vtb, Yb);
  gemm_bt<1><<<dim3(64, 8), 256, 0, stream>>>(Yb, woT, bo, out, nullptr, nullptr, nullptr, 1024);
}

// Round 2
// 312.622 us; speedup vs baseline: 1.7859x; 1.7859x over previous
//
#include <hip/hip_runtime.h>
#include <hip/hip_bf16.h>
#include <stdint.h>

typedef __attribute__((ext_vector_type(8))) __bf16 bf16x8;
typedef __attribute__((ext_vector_type(4))) float f32x4;

#define MFMA16(a, b, c) __builtin_amdgcn_mfma_f32_16x16x32_bf16((a), (b), (c), 0, 0, 0)

static __device__ __forceinline__ void gload_lds16(const void* g, void* l) {
  __builtin_amdgcn_global_load_lds(
      reinterpret_cast<const __attribute__((address_space(1))) uint32_t*>(
          reinterpret_cast<uintptr_t>(g)),
      reinterpret_cast<__attribute__((address_space(3))) uint32_t*>(
          reinterpret_cast<uintptr_t>(l)),
      16, 0, 0);
}

// ---------------- fp32 -> bf16 copy convert (vectorized) ----------------
__global__ void cvt_f32_bf16(const float* __restrict__ in, __bf16* __restrict__ out, int n) {
  int i = (blockIdx.x * blockDim.x + threadIdx.x) * 8;
  if (i >= n) return;
  float4 a = *(const float4*)(in + i);
  float4 b = *(const float4*)(in + i + 4);
  bf16x8 o;
  o[0] = (__bf16)a.x; o[1] = (__bf16)a.y; o[2] = (__bf16)a.z; o[3] = (__bf16)a.w;
  o[4] = (__bf16)b.x; o[5] = (__bf16)b.y; o[6] = (__bf16)b.z; o[7] = (__bf16)b.w;
  *(bf16x8*)(out + i) = o;
}

// ---------- transpose + convert: in[R][C] f32 -> out[C][R] bf16 ----------
__global__ void transpose_cvt(const float* __restrict__ in, __bf16* __restrict__ out,
                              int R, int C) {
  __shared__ float tile[32][33];
  int c0 = blockIdx.x * 32, r0 = blockIdx.y * 32;
  int tx = threadIdx.x, ty = threadIdx.y;  // 32 x 8
#pragma unroll
  for (int i = 0; i < 4; i++)
    tile[ty + i * 8][tx] = in[(size_t)(r0 + ty + i * 8) * C + c0 + tx];
  __syncthreads();
#pragma unroll
  for (int i = 0; i < 4; i++)
    out[(size_t)(c0 + ty + i * 8) * R + r0 + tx] = (__bf16)tile[tx][ty + i * 8];
}

// ---------- V [BH][2048][64] -> Vt [BH][64][2048] (bf16) ----------
__global__ void transpose_v(const __bf16* __restrict__ V, __bf16* __restrict__ Vt) {
  __shared__ __bf16 tile[64][72];
  int bh = blockIdx.y, s0 = blockIdx.x * 64;
  int t = threadIdx.x;          // 256
  int r = t >> 2, cq = (t & 3) * 16;
  const __bf16* src = V + ((size_t)bh * 2048 + s0 + r) * 64 + cq;
  bf16x8 v0 = *(const bf16x8*)src;
  bf16x8 v1 = *(const bf16x8*)(src + 8);
#pragma unroll
  for (int j = 0; j < 8; j++) { tile[r][cq + j] = v0[j]; tile[r][cq + 8 + j] = v1[j]; }
  __syncthreads();
  int d = t >> 2, sq = (t & 3) * 16;
  bf16x8 o0, o1;
#pragma unroll
  for (int j = 0; j < 8; j++) { o0[j] = tile[sq + j][d]; o1[j] = tile[sq + 8 + j][d]; }
  __bf16* dst = Vt + ((size_t)bh * 64 + d) * 2048 + s0 + sq;
  *(bf16x8*)dst = o0;
  *(bf16x8*)(dst + 8) = o1;
}

// ---------------- GEMM: C[M,N] = A[M,1024] @ Bt[N,1024]^T ----------------
template <int EPI>
__global__ __launch_bounds__(256) void gemm_bt(
    const __bf16* __restrict__ A, const __bf16* __restrict__ Bt,
    const float* __restrict__ bias, float* __restrict__ Cf,
    __bf16* __restrict__ Qb, __bf16* __restrict__ Kb, __bf16* __restrict__ Vb, int N) {
  __shared__ __bf16 lA[128 * 32];
  __shared__ __bf16 lB[128 * 32];
  const int tM = blockIdx.x, tN = blockIdx.y;
  const int tid = threadIdx.x;
  const int w = tid >> 6, lane = tid & 63;
  const int wr = w >> 1, wc = w & 1;
  const int lr = lane & 15, lg = lane >> 4;

  const __bf16* As0 = A + (size_t)(tM * 128 + w * 16 + (lane >> 2)) * 1024 + (lane & 3) * 8;
  const __bf16* Bs0 = Bt + (size_t)(tN * 128 + w * 16 + (lane >> 2)) * 1024 + (lane & 3) * 8;
  __bf16* lA0 = &lA[w * 512];
  __bf16* lA1 = &lA[w * 512 + 2048];
  __bf16* lB0 = &lB[w * 512];
  __bf16* lB1 = &lB[w * 512 + 2048];

  f32x4 acc[4][4];
#pragma unroll
  for (int m = 0; m < 4; m++)
#pragma unroll
    for (int n = 0; n < 4; n++) acc[m][n] = f32x4{0.f, 0.f, 0.f, 0.f};

  for (int k0 = 0; k0 < 1024; k0 += 32) {
    gload_lds16(As0 + k0, lA0);
    gload_lds16(As0 + 64 * 1024 + k0, lA1);
    gload_lds16(Bs0 + k0, lB0);
    gload_lds16(Bs0 + 64 * 1024 + k0, lB1);
    __syncthreads();
    bf16x8 af[4], bfr[4];
#pragma unroll
    for (int m = 0; m < 4; m++)
      af[m] = *(const bf16x8*)&lA[(wr * 64 + m * 16 + lr) * 32 + lg * 8];
#pragma unroll
    for (int n = 0; n < 4; n++)
      bfr[n] = *(const bf16x8*)&lB[(wc * 64 + n * 16 + lr) * 32 + lg * 8];
#pragma unroll
    for (int m = 0; m < 4; m++)
#pragma unroll
      for (int n = 0; n < 4; n++) acc[m][n] = MFMA16(af[m], bfr[n], acc[m][n]);
    __syncthreads();
  }

#pragma unroll
  for (int m = 0; m < 4; m++) {
#pragma unroll
    for (int n = 0; n < 4; n++) {
      int row0 = tM * 128 + wr * 64 + m * 16 + lg * 4;
      int col = tN * 128 + wc * 64 + n * 16 + lr;
      float bv = bias[col];
      if (EPI == 0) {
        int which = col >> 10, rem = col & 1023;
        int hh = rem >> 6, dd = rem & 63;
        __bf16* dst = (which == 0) ? Qb : ((which == 1) ? Kb : Vb);
#pragma unroll
        for (int r = 0; r < 4; r++) {
          int row = row0 + r;
          int b = row >> 11, s = row & 2047;
          dst[((size_t)(b * 16 + hh) * 2048 + s) * 64 + dd] = (__bf16)(acc[m][n][r] + bv);
        }
      } else {
#pragma unroll
        for (int r = 0; r < 4; r++)
          Cf[(size_t)(row0 + r) * N + col] = acc[m][n][r] + bv;
      }
    }
  }
}

// ---------------- flash causal attention (LDS-staged, double-buffered) ----------------
// grid: (16 q-tiles of 128 [reversed], 64 bh), block 256 (4 waves x 32 q-rows).
// Q,K: [BH][2048][64] bf16; Vt: [BH][64][2048] bf16; Y: [B,S,1024] bf16
__global__ __launch_bounds__(256) void attn_fwd(
    const __bf16* __restrict__ Q, const __bf16* __restrict__ K,
    const __bf16* __restrict__ Vt, __bf16* __restrict__ Y) {
  const int qt = (int)gridDim.x - 1 - (int)blockIdx.x;  // big tiles first
  const int bh = blockIdx.y;
  const int w = threadIdx.x >> 6, lane = threadIdx.x & 63;
  const int lr = lane & 15, lg = lane >> 4;
  const int b = bh >> 4, h = bh & 15;
  const int qbase = qt * 128 + w * 32;
  const __bf16* Qp = Q + (size_t)bh * 2048 * 64;
  const __bf16* Kp = K + (size_t)bh * 2048 * 64;
  const __bf16* Vp = Vt + (size_t)bh * 64 * 2048;

  // K tile [64 kv][64 d], V tile [64 d][64 kv]; XOR-swizzled byte ^= (row&7)<<4
  __shared__ __bf16 Kl[2][4096];
  __shared__ __bf16 Vl[2][4096];
  __shared__ __bf16 Pl[4][32 * 72];
  __bf16* Pw = Pl[w];

  // Q fragments: rows qbase + m*16 + lr, k = c*32 + lg*8
  bf16x8 aq[2][2];
#pragma unroll
  for (int m = 0; m < 2; m++)
#pragma unroll
    for (int c = 0; c < 2; c++)
      aq[m][c] = *(const bf16x8*)&Qp[(size_t)(qbase + m * 16 + lr) * 64 + c * 32 + lg * 8];

  f32x4 acc_o[2][4];
#pragma unroll
  for (int m = 0; m < 2; m++)
#pragma unroll
    for (int dn = 0; dn < 4; dn++) acc_o[m][dn] = f32x4{0.f, 0.f, 0.f, 0.f};
  float m_run[2][4], l_run[2][4];
#pragma unroll
  for (int m = 0; m < 2; m++)
#pragma unroll
    for (int r = 0; r < 4; r++) { m_run[m][r] = -1e30f; l_run[m][r] = 0.f; }

  const float scale = 0.125f;
  const int nt = 2 * qt + 2;

  // stage kv block kv0_ into buffer buf (swizzled source, linear LDS dest)
  auto stage = [&](int buf, int kv0_) {
#pragma unroll
    for (int is = 0; is < 2; is++) {
      int rr = w * 16 + is * 8 + (lane >> 3);
      int sc = ((lane & 7) ^ (rr & 7)) * 8;
      gload_lds16(Kp + (size_t)(kv0_ + rr) * 64 + sc, &Kl[buf][(w * 16 + is * 8) * 64]);
      gload_lds16(Vp + (size_t)rr * 2048 + kv0_ + sc, &Vl[buf][(w * 16 + is * 8) * 64]);
    }
  };

  stage(0, 0);
  __syncthreads();
  int cur = 0;

  for (int t = 0; t < nt; ++t) {
    const int kv0 = t * 64;
    if (t + 1 < nt) stage(cur ^ 1, kv0 + 64);  // prefetch next tile (T14: issue early)

    if (kv0 <= qbase + 31) {
      // ---- QK^T from LDS (swizzled reads, conflict-free) ----
      f32x4 s4[2][4];
#pragma unroll
      for (int m = 0; m < 2; m++)
#pragma unroll
        for (int n = 0; n < 4; n++) s4[m][n] = f32x4{0.f, 0.f, 0.f, 0.f};
#pragma unroll
      for (int c = 0; c < 2; c++) {
#pragma unroll
        for (int n = 0; n < 4; n++) {
          int kr = n * 16 + lr;
          int off = kr * 64 + (((c * 64 + lg * 16) ^ ((kr & 7) << 4)) >> 1);
          bf16x8 bk = *(const bf16x8*)&Kl[cur][off];
#pragma unroll
          for (int m = 0; m < 2; m++) s4[m][n] = MFMA16(aq[m][c], bk, s4[m][n]);
        }
      }

      // ---- online softmax (defer-max THR=8, deferred l-reduce) ----
      const bool fullvis = (kv0 + 63 <= qbase);
      float vmax_[2][4];
      bool need = false;
#pragma unroll
      for (int m = 0; m < 2; m++) {
#pragma unroll
        for (int r = 0; r < 4; r++) {
          const int qrow = qbase + m * 16 + lg * 4 + r;
          float vmax = -1e30f;
#pragma unroll
          for (int n = 0; n < 4; n++) {
            float sv = s4[m][n][r] * scale;
            if (!fullvis && (kv0 + n * 16 + lr > qrow)) sv = -1e30f;
            s4[m][n][r] = sv;
            vmax = fmaxf(vmax, sv);
          }
          vmax = fmaxf(vmax, __shfl_xor(vmax, 1));
          vmax = fmaxf(vmax, __shfl_xor(vmax, 2));
          vmax = fmaxf(vmax, __shfl_xor(vmax, 4));
          vmax = fmaxf(vmax, __shfl_xor(vmax, 8));
          vmax_[m][r] = vmax;
          need = need || (vmax > m_run[m][r] + 8.f);
        }
      }
      if (__any(need)) {
#pragma unroll
        for (int m = 0; m < 2; m++)
#pragma unroll
          for (int r = 0; r < 4; r++) {
            float mnew = fmaxf(m_run[m][r], vmax_[m][r]);
            float alpha = __expf(m_run[m][r] - mnew);
            m_run[m][r] = mnew;
            l_run[m][r] *= alpha;
#pragma unroll
            for (int dn = 0; dn < 4; dn++) acc_o[m][dn][r] *= alpha;
          }
      }
#pragma unroll
      for (int m = 0; m < 2; m++)
#pragma unroll
        for (int r = 0; r < 4; r++) {
          float rs = 0.f;
#pragma unroll
          for (int n = 0; n < 4; n++) {
            float e = __expf(s4[m][n][r] - m_run[m][r]);
            s4[m][n][r] = e;
            rs += e;
          }
          l_run[m][r] += rs;  // per-lane partial; reduced at epilogue
        }

      // ---- P (C-layout) -> LDS -> A-layout fragments ----
#pragma unroll
      for (int m = 0; m < 2; m++)
#pragma unroll
        for (int r = 0; r < 4; r++)
#pragma unroll
          for (int n = 0; n < 4; n++)
            Pw[(m * 16 + lg * 4 + r) * 72 + n * 16 + lr] = (__bf16)s4[m][n][r];
      bf16x8 ap[2][2];
#pragma unroll
      for (int m = 0; m < 2; m++)
#pragma unroll
        for (int cc = 0; cc < 2; cc++)
          ap[m][cc] = *(const bf16x8*)&Pw[(m * 16 + lr) * 72 + cc * 32 + lg * 8];

      // ---- PV from LDS V (swizzled reads) ----
#pragma unroll
      for (int dn = 0; dn < 4; dn++) {
        int d = dn * 16 + lr;
#pragma unroll
        for (int cc = 0; cc < 2; cc++) {
          int off = d * 64 + (((cc * 64 + lg * 16) ^ ((d & 7) << 4)) >> 1);
          bf16x8 bv = *(const bf16x8*)&Vl[cur][off];
#pragma unroll
          for (int m = 0; m < 2; m++) acc_o[m][dn] = MFMA16(ap[m][cc], bv, acc_o[m][dn]);
        }
      }
    }

    __syncthreads();  // drains stage (vmcnt) + guards buffer reuse
    cur ^= 1;
  }

  // epilogue: reduce l over the 16 lr lanes, normalize, store
#pragma unroll
  for (int m = 0; m < 2; m++) {
#pragma unroll
    for (int r = 0; r < 4; r++) {
      float lsum = l_run[m][r];
      lsum += __shfl_xor(lsum, 1);
      lsum += __shfl_xor(lsum, 2);
      lsum += __shfl_xor(lsum, 4);
      lsum += __shfl_xor(lsum, 8);
      float inv = 1.f / lsum;
      int row = b * 2048 + qbase + m * 16 + lg * 4 + r;
#pragma unroll
      for (int dn = 0; dn < 4; dn++)
        Y[(size_t)row * 1024 + h * 64 + dn * 16 + lr] = (__bf16)(acc_o[m][dn][r] * inv);
    }
  }
}

extern "C" void kernel_launch(void* const* d_in, const int* in_sizes, int n_in,
                              void* d_out, int out_size, void* d_ws, size_t ws_size,
                              hipStream_t stream) {
  const float* x = (const float*)d_in[0];
  const float* wqkv = (const float*)d_in[1];
  const float* bqkv = (const float*)d_in[2];
  const float* wo = (const float*)d_in[3];
  const float* bo = (const float*)d_in[4];
  float* out = (float*)d_out;

  __bf16* ws = (__bf16*)d_ws;
  __bf16* xb = ws;                      // 8,388,608 elems (reused as Y later)
  __bf16* wqkvT = xb + 8388608;         // 3,145,728
  __bf16* woT = wqkvT + 3145728;        // 1,048,576
  __bf16* Qb = woT + 1048576;           // 8,388,608
  __bf16* Kb = Qb + 8388608;            // 8,388,608
  __bf16* Vb = Kb + 8388608;            // 8,388,608
  __bf16* Vtb = Vb + 8388608;           // 8,388,608
  __bf16* Yb = xb;                      // alias: xb dead after gemm1

  cvt_f32_bf16<<<4096, 256, 0, stream>>>(x, xb, 8388608);
  dim3 tb(32, 8);
  transpose_cvt<<<dim3(96, 32), tb, 0, stream>>>(wqkv, wqkvT, 1024, 3072);
  transpose_cvt<<<dim3(32, 32), tb, 0, stream>>>(wo, woT, 1024, 1024);
  gemm_bt<0><<<dim3(64, 24), 256, 0, stream>>>(xb, wqkvT, bqkv, nullptr, Qb, Kb, Vb, 3072);
  transpose_v<<<dim3(32, 64), 256, 0, stream>>>(Vb, Vtb);
  attn_fwd<<<dim3(16, 64), 256, 0, stream>>>(Qb, Kb, Vtb, Yb);
  gemm_bt<1><<<dim3(64, 8), 256, 0, stream>>>(Yb, woT, bo, out, nullptr, nullptr, nullptr, 1024);
}